// Round 7
// baseline (575.508 us; speedup 1.0000x reference)
//
#include <hip/hip_runtime.h>
#include <hip/hip_bf16.h>
#include <math.h>

#define N_ENT   50000
#define N_REL   237
#define N_TYPE  4000
#define DE      100
#define NOUT    128
#define DT      200
#define N_EDGE  800000
#define B_SZ    4096
#define ALPHA   0.2f
#define EPS     1e-5f
#define NUM_FILT 32
#define CONV_W_OUT 60
#define POOL_W  30
#define FC_LEN  960
#define KP      224

typedef unsigned short ushort_t;
typedef __attribute__((ext_vector_type(8))) short bf16x8;
typedef __attribute__((ext_vector_type(4))) float f32x4;

// ---------------- zero fill ----------------
__global__ void k_fill0(float4* p, int n) {
    int i = blockIdx.x * blockDim.x + threadIdx.x;
    if (i < n) p[i] = make_float4(0.f, 0.f, 0.f, 0.f);
}

// ---------------- diagnostic fill (f32) ----------------
__global__ void k_fillconst(float* p, long n, float val) {
    long i = (long)blockIdx.x * blockDim.x + threadIdx.x;
    long stride = (long)gridDim.x * blockDim.x;
    for (; i < n; i += stride) p[i] = val;
}

// ---------------- batch membership flags ----------------
__global__ void k_flags(const int* xb, int* flags) {
    int i = blockIdx.x * blockDim.x + threadIdx.x;
    if (i < B_SZ) flags[xb[i]] = 1;
}

// ---------------- compact slot ids ----------------
__global__ void k_slots(int* flags, int* counter) {
    int i = blockIdx.x * blockDim.x + threadIdx.x;
    if (i >= N_ENT) return;
    if (flags[i]) flags[i] = 1 + atomicAdd(counter, 1);
}

// ---------------- wa1/wa2/rw precompute (f32 inputs) ----------------
__global__ void k_prep(const float* Wf, const float* a_vec, const float* Rw,
                       float* wa1, float* wa2, float* rw) {
    __shared__ float sa[2 * NOUT];
    __shared__ float swa2[DE];
    int t = threadIdx.x;
    sa[t] = a_vec[t];
    __syncthreads();
    if (t < DE) {
        float s1 = 0.f, s2 = 0.f;
        for (int j = 0; j < NOUT; j++) {
            float w = Wf[t * NOUT + j];
            s1 += w * sa[j];
            s2 += w * sa[NOUT + j];
        }
        wa1[t] = s1; wa2[t] = s2; swa2[t] = s2;
    }
    __syncthreads();
    if (t < N_REL) {
        float s = 0.f;
        for (int k = 0; k < DE; k++) s += Rw[t * DE + k] * swa2[k];
        rw[t] = s;
    }
}

// ---------------- per-entity dots: ha = E_w . wa1, ew = E_w . wa2 ----------------
__global__ void k_entdots(const float* Ew, const float* wa1, const float* wa2,
                          float* ha, float* ew) {
    int wid = blockIdx.x * 4 + (threadIdx.x >> 6);
    int lane = threadIdx.x & 63;
    if (wid >= N_ENT) return;
    float s1 = 0.f, s2 = 0.f;
    if (lane < DE / 2) {
        const float2* p = (const float2*)(Ew + (size_t)wid * DE);
        float2 v = p[lane];
        s1 = v.x * wa1[2 * lane] + v.y * wa1[2 * lane + 1];
        s2 = v.x * wa2[2 * lane] + v.y * wa2[2 * lane + 1];
    }
    for (int off = 32; off > 0; off >>= 1) {
        s1 += __shfl_down(s1, off);
        s2 += __shfl_down(s2, off);
    }
    if (lane == 0) { ha[wid] = s1; ew[wid] = s2; }
}

__device__ __forceinline__ float edge_ex(const float* ha, const float* ew, const float* rw,
                                         int dst, int src, int r) {
    float s = ha[dst] + ew[src] - rw[r];
    s = s >= 0.f ? s : ALPHA * s;
    return expf(s);
}

// ---------------- edge pass 1: denom[slot] += exp(leaky(score)) ----------------
__global__ void k_edge1(const int* ei, const int* et, const int* flags,
                        const float* ha, const float* ew, const float* rw,
                        float* denom) {
    int e = blockIdx.x * blockDim.x + threadIdx.x;
    if (e >= N_EDGE) return;
    int dst = ei[N_EDGE + e];
    int s = flags[dst];
    if (!s) return;
    float ex = edge_ex(ha, ew, rw, dst, ei[e], et[e]);
    atomicAdd(&denom[s - 1], ex);
}

// ---------------- edge pass 2: aggc[slot] += att * (E_w[src] - R_w[et]) ----------------
__global__ void k_edge2(const int* ei, const int* et, const int* flags,
                        const float* Ew, const float* Rw,
                        const float* ha, const float* ew, const float* rw,
                        const float* denom, float* aggc) {
    int e = blockIdx.x * 4 + (threadIdx.x >> 6);
    int lane = threadIdx.x & 63;
    if (e >= N_EDGE) return;
    int dst = ei[N_EDGE + e];
    int sfl = flags[dst];
    if (!sfl) return;
    int slot = sfl - 1;
    int src = ei[e];
    int r = et[e];
    float ex = edge_ex(ha, ew, rw, dst, src, r);   // identical recompute to pass 1
    float att = ex / (denom[slot] + 1e-16f);
    if (lane >= DE / 2) return;
    const float2* ps = (const float2*)(Ew + (size_t)src * DE);
    const float2* pr = (const float2*)(Rw + (size_t)r * DE);
    float2 vs = ps[lane], vr = pr[lane];
    float* dp = aggc + (size_t)slot * DE + 2 * lane;
    atomicAdd(dp, att * (vs.x - vr.x));
    atomicAdd(dp + 1, att * (vs.y - vr.y));
}

// ---------------- gather + [100]x[100,128] + elu + bn1 stats ----------------
__global__ void k_gather(const int* xb, const int* flags, const float* aggc,
                         const float* Wf, float* ebuf, float* stats) {
    __shared__ float row[DE];
    __shared__ float rs[NOUT], rq[NOUT];
    int b = blockIdx.x, t = threadIdx.x;
    int slot = flags[xb[b]] - 1;
    if (t < DE) row[t] = aggc[(size_t)slot * DE + t];
    __syncthreads();
    float acc = 0.f;
    for (int k = 0; k < DE; k++) acc += row[k] * Wf[k * NOUT + t];
    float ev = acc > 0.f ? acc : expm1f(acc);
    ebuf[b * NOUT + t] = ev;
    rs[t] = ev; rq[t] = ev * ev;
    __syncthreads();
    for (int s = 64; s > 0; s >>= 1) {
        if (t < s) { rs[t] += rs[t + s]; rq[t] += rq[t + s]; }
        __syncthreads();
    }
    if (t == 0) { atomicAdd(&stats[0], rs[0]); atomicAdd(&stats[1], rq[0]); }
}

// ---------------- conv pass 1: bn1 + conv -> bn3 stats ----------------
__global__ void k_conv1(const float* ebuf, const float* stats,
                        const float* bn1g, const float* bn1b,
                        const float* convw, const float* convb,
                        float* bn3s) {
    __shared__ float xn[NOUT];
    __shared__ float cw[NUM_FILT * 9];
    __shared__ float cb[NUM_FILT];
    __shared__ float rs[256], rq[256];
    int b = blockIdx.x, t = threadIdx.x;
    float Ntot = (float)(B_SZ * NOUT);
    float mean = stats[0] / Ntot;
    float var = stats[1] / Ntot - mean * mean;
    float sc = bn1g[0] * rsqrtf(var + EPS);
    float sh = bn1b[0] - mean * sc;
    if (t < NOUT) xn[t] = ebuf[b * NOUT + t] * sc + sh;
    for (int i = t; i < NUM_FILT * 9; i += 256) cw[i] = convw[i];
    if (t < NUM_FILT) cb[t] = convb[t];
    __syncthreads();
    int c = t >> 3, ws = t & 7;
    float lsum = 0.f, lsq = 0.f;
    for (int i = 0; i < 8; i++) {
        int w = ws + 8 * i;
        if (w < CONV_W_OUT) {
            float y = cb[c];
            #pragma unroll
            for (int j = 0; j < 9; j++) y += xn[2 * w + j] * cw[c * 9 + j];
            lsum += y; lsq += y * y;
        }
    }
    rs[t] = lsum; rq[t] = lsq;
    __syncthreads();
    if (t < NUM_FILT) {
        float s = 0.f, q = 0.f;
        for (int i = 0; i < 8; i++) { s += rs[t * 8 + i]; q += rq[t * 8 + i]; }
        atomicAdd(&bn3s[t], s);
        atomicAdd(&bn3s[NUM_FILT + t], q);
    }
}

// ---------------- conv pass 2: conv + bn3 + relu + pool -> pooled bf16 ----------------
__global__ void k_conv2(const float* ebuf, const float* stats, const float* bn3s,
                        const float* bn1g, const float* bn1b,
                        const float* bn3g, const float* bn3b,
                        const float* convw, const float* convb,
                        __hip_bfloat16* pooled) {
    __shared__ float xn[NOUT];
    __shared__ float cw[NUM_FILT * 9];
    __shared__ float cb[NUM_FILT];
    int b = blockIdx.x, t = threadIdx.x;
    float Ntot = (float)(B_SZ * NOUT);
    float mean = stats[0] / Ntot;
    float var = stats[1] / Ntot - mean * mean;
    float sc = bn1g[0] * rsqrtf(var + EPS);
    float sh = bn1b[0] - mean * sc;
    if (t < NOUT) xn[t] = ebuf[b * NOUT + t] * sc + sh;
    for (int i = t; i < NUM_FILT * 9; i += 256) cw[i] = convw[i];
    if (t < NUM_FILT) cb[t] = convb[t];
    __syncthreads();
    int c = t >> 3, ws = t & 7;
    float Nc = (float)(B_SZ * CONV_W_OUT);
    float m3 = bn3s[c] / Nc;
    float v3 = bn3s[NUM_FILT + c] / Nc - m3 * m3;
    float sc3 = bn3g[c] * rsqrtf(v3 + EPS);
    float sh3 = bn3b[c] - m3 * sc3;
    for (int i = 0; i < 4; i++) {
        int w2 = ws + 8 * i;
        if (w2 < POOL_W) {
            float y0 = cb[c], y1 = cb[c];
            int w = 2 * w2;
            #pragma unroll
            for (int j = 0; j < 9; j++) {
                float cwv = cw[c * 9 + j];
                y0 += xn[2 * w + j] * cwv;
                y1 += xn[2 * w + 2 + j] * cwv;
            }
            float p0 = fmaxf(y0 * sc3 + sh3, 0.f);
            float p1 = fmaxf(y1 * sc3 + sh3, 0.f);
            pooled[((size_t)b * NUM_FILT + c) * POOL_W + w2] = __float2bfloat16(fmaxf(p0, p1));
        }
    }
}

// ---------------- repack fc_w f32 [200,960] -> bf16 [224,960] ----------------
__global__ void k_pad_fcw(const float* fcw, __hip_bfloat16* bfc) {
    int i = blockIdx.x * blockDim.x + threadIdx.x;
    if (i >= KP * FC_LEN) return;
    bfc[i] = __float2bfloat16((i < DT * FC_LEN) ? fcw[i] : 0.f);
}

// ---------------- repack T_w f32 [4000,200] -> bf16 [4000,224] ----------------
__global__ void k_pad_tw(const float* tw, __hip_bfloat16* b2) {
    int i = blockIdx.x * blockDim.x + threadIdx.x;
    if (i >= N_TYPE * KP) return;
    int n = i / KP, k = i - n * KP;
    b2[i] = __float2bfloat16((k < DT) ? tw[n * DT + k] : 0.f);
}

// ---------------- MFMA GEMM: A[M,K] bf16 row-major, B[N,K] bf16 row-major ----------------
// MODE 0: C = A@B^T + bias (f32).  MODE 1: sigmoid(A@B^T + bias) (f32)  — OUTPUT IS F32
template<int MODE>
__launch_bounds__(256)
__global__ void k_gemm(const ushort_t* A, const ushort_t* Bm, const float* bias,
                       int K, int ldc, int nbias, float* Cf) {
    int wave = threadIdx.x >> 6, lane = threadIdx.x & 63;
    int m0 = blockIdx.x * 128 + wave * 32;
    int n0 = blockIdx.y * 32;
    int rsel = lane & 15, ksel = (lane >> 4) * 8;
    const ushort_t* pa0 = A + (size_t)(m0 + rsel) * K + ksel;
    const ushort_t* pa1 = pa0 + (size_t)16 * K;
    const ushort_t* pb0 = Bm + (size_t)(n0 + rsel) * K + ksel;
    const ushort_t* pb1 = pb0 + (size_t)16 * K;
    f32x4 acc00 = {0.f, 0.f, 0.f, 0.f};
    f32x4 acc01 = acc00, acc10 = acc00, acc11 = acc00;
    for (int k = 0; k < K; k += 32) {
        bf16x8 a0 = *(const bf16x8*)(pa0 + k);
        bf16x8 a1 = *(const bf16x8*)(pa1 + k);
        bf16x8 b0 = *(const bf16x8*)(pb0 + k);
        bf16x8 b1 = *(const bf16x8*)(pb1 + k);
        acc00 = __builtin_amdgcn_mfma_f32_16x16x32_bf16(a0, b0, acc00, 0, 0, 0);
        acc01 = __builtin_amdgcn_mfma_f32_16x16x32_bf16(a0, b1, acc01, 0, 0, 0);
        acc10 = __builtin_amdgcn_mfma_f32_16x16x32_bf16(a1, b0, acc10, 0, 0, 0);
        acc11 = __builtin_amdgcn_mfma_f32_16x16x32_bf16(a1, b1, acc11, 0, 0, 0);
    }
    int rbase = (lane >> 4) * 4, col = lane & 15;
    auto store_tile = [&](f32x4 acc, int mi, int nj) {
        #pragma unroll
        for (int r2 = 0; r2 < 4; r2++) {
            int row = m0 + mi * 16 + rbase + r2;
            int cc = n0 + nj * 16 + col;
            float v = acc[r2];
            if (MODE == 0) {
                float bb = (cc < nbias) ? bias[cc] : 0.f;
                Cf[(size_t)row * ldc + cc] = v + bb;
            } else {
                float sg = 1.f / (1.f + expf(-(v + bias[cc])));
                Cf[(size_t)row * ldc + cc] = sg;
            }
        }
    };
    store_tile(acc00, 0, 0); store_tile(acc01, 0, 1);
    store_tile(acc10, 1, 0); store_tile(acc11, 1, 1);
}

// ---------------- bn2 stats ----------------
__global__ void k_bn2stats(const float* fcout, const float* g, const float* bb,
                           float* scale, float* shift) {
    __shared__ float rs[256], rq[256];
    int t = blockIdx.x;
    int tid = threadIdx.x;
    float s = 0.f, q = 0.f;
    for (int b = tid; b < B_SZ; b += 256) {
        float v = fcout[(size_t)b * KP + t];
        s += v; q += v * v;
    }
    rs[tid] = s; rq[tid] = q;
    __syncthreads();
    for (int k = 128; k > 0; k >>= 1) {
        if (tid < k) { rs[tid] += rs[tid + k]; rq[tid] += rq[tid + k]; }
        __syncthreads();
    }
    if (tid == 0) {
        float mean = rs[0] / (float)B_SZ;
        float var = rq[0] / (float)B_SZ - mean * mean;
        float sc = g[t] * rsqrtf(var + EPS);
        scale[t] = sc;
        shift[t] = bb[t] - mean * sc;
    }
}

// ---------------- bn2 apply + relu -> bf16 A2 [B,224] ----------------
__global__ void k_bn2apply(const float* fcout, const float* scale, const float* shift,
                           __hip_bfloat16* a2) {
    int i = blockIdx.x * blockDim.x + threadIdx.x;
    if (i >= B_SZ * KP) return;
    int t = i % KP;
    float v = 0.f;
    if (t < DT) {
        v = fcout[i] * scale[t] + shift[t];
        v = fmaxf(v, 0.f);
    }
    a2[i] = __float2bfloat16(v);
}

extern "C" void kernel_launch(void* const* d_in, const int* in_sizes, int n_in,
                              void* d_out, int out_size, void* d_ws, size_t ws_size,
                              hipStream_t stream) {
    (void)in_sizes; (void)n_in;
    const int*   x_batch = (const int*)d_in[0];
    const int*   ei      = (const int*)d_in[1];
    const int*   etype   = (const int*)d_in[2];
    const float* E_w     = (const float*)d_in[3];    // f32 (R4 probe)
    const float* R_w     = (const float*)d_in[4];
    const float* T_w     = (const float*)d_in[5];
    const float* W_f     = (const float*)d_in[6];
    const float* a_vec   = (const float*)d_in[7];
    const float* conv_w  = (const float*)d_in[8];
    const float* conv_b  = (const float*)d_in[9];
    const float* bn1_g   = (const float*)d_in[10];
    const float* bn1_b   = (const float*)d_in[11];
    const float* bn3_g   = (const float*)d_in[12];
    const float* bn3_b   = (const float*)d_in[13];
    const float* bn2_g   = (const float*)d_in[14];
    const float* bn2_b   = (const float*)d_in[15];
    const float* fc_w    = (const float*)d_in[16];
    const float* fc_b    = (const float*)d_in[17];
    const float* b_bias  = (const float*)d_in[18];
    float* out           = (float*)d_out;            // f32 (R5/R6 signature arithmetic)
    long outn = (long)out_size;

    const size_t WS_NEEDED = 4787712;
    if (ws_size < WS_NEEDED) {
        k_fillconst<<<2048, 256, 0, stream>>>(out, outn, 50.f);
        return;
    }
    char* ws = (char*)d_ws;
    float* wa1      = (float*)(ws + 0);
    float* wa2      = (float*)(ws + 512);
    float* rw       = (float*)(ws + 1024);
    float* stats    = (float*)(ws + 2048);       // [0..1] bn1, [2..65] bn3
    int*   counter  = (int*)  (ws + 2560);
    float* bn2scale = (float*)(ws + 2816);
    float* bn2shift = (float*)(ws + 3840);
    // graph region (dead after k_gather)
    float* ha       = (float*)(ws + 5120);
    float* ew       = (float*)(ws + 205312);
    int*   flags    = (int*)  (ws + 405504);
    float* denom    = (float*)(ws + 605696);
    float* aggc     = (float*)(ws + 622080);     // [4096,100] f32; region ends 2,260,480
    __hip_bfloat16* a2 = (__hip_bfloat16*)(ws + 5120);   // overlay graph region
    float* ebuf     = (float*)(ws + 2260480);    // [4096,128] f32; dead after conv2
    __hip_bfloat16* b2 = (__hip_bfloat16*)(ws + 2260480);// overlay ebuf
    __hip_bfloat16* bfc = (__hip_bfloat16*)(ws + 4357632);
    // scratch inside d_out (65.54 MB as f32; final GEMM rewrites all of it)
    __hip_bfloat16* pooled = (__hip_bfloat16*)((char*)d_out + 0);       // 7.86 MB
    float* fcout    = (float*)((char*)d_out + 8388608);                 // 3.67 MB

    // 1. zero stats/counter + graph region (flags..denom..aggc)
    k_fill0<<<1, 64, 0, stream>>>((float4*)stats, 48);
    k_fill0<<<453, 256, 0, stream>>>((float4*)flags, 1854976 / 16);
    // 2. membership flags -> compact slots
    k_flags<<<16, 256, 0, stream>>>(x_batch, flags);
    k_slots<<<196, 256, 0, stream>>>(flags, counter);
    // 3. precompute wa1/wa2/rw
    k_prep<<<1, 256, 0, stream>>>(W_f, a_vec, R_w, wa1, wa2, rw);
    // 4. per-entity dots
    k_entdots<<<12500, 256, 0, stream>>>(E_w, wa1, wa2, ha, ew);
    // 5. edge pass 1
    k_edge1<<<3125, 256, 0, stream>>>(ei, etype, flags, ha, ew, rw, denom);
    // 6. edge pass 2
    k_edge2<<<200000, 256, 0, stream>>>(ei, etype, flags, E_w, R_w, ha, ew, rw, denom, aggc);
    // 7. gather + project + elu + bn1 stats
    k_gather<<<4096, 128, 0, stream>>>(x_batch, flags, aggc, W_f, ebuf, stats);
    // 8. conv pass 1: bn3 stats
    k_conv1<<<4096, 256, 0, stream>>>(ebuf, stats, bn1_g, bn1_b, conv_w, conv_b, stats + 2);
    // 9. conv pass 2: conv + bn3 + relu + pool
    k_conv2<<<4096, 256, 0, stream>>>(ebuf, stats, stats + 2, bn1_g, bn1_b, bn3_g, bn3_b,
                                      conv_w, conv_b, pooled);
    // 10. repack fc_w (f32 -> bf16, K-pad)
    k_pad_fcw<<<840, 256, 0, stream>>>(fc_w, bfc);
    // 11. FC GEMM: [4096,960] @ [224,960]^T -> fcout f32
    k_gemm<0><<<dim3(32, 7), 256, 0, stream>>>((const ushort_t*)pooled, (const ushort_t*)bfc,
                                               fc_b, FC_LEN, KP, DT, fcout);
    // 12. bn2 stats + apply
    k_bn2stats<<<200, 256, 0, stream>>>(fcout, bn2_g, bn2_b, bn2scale, bn2shift);
    k_bn2apply<<<3584, 256, 0, stream>>>(fcout, bn2scale, bn2shift, a2);
    // 13. repack T_w (f32 -> bf16, K-pad)
    k_pad_tw<<<3500, 256, 0, stream>>>(T_w, b2);
    // 14. logits GEMM + bias + sigmoid -> F32 out (65.5 MB, rewrites all scratch)
    k_gemm<1><<<dim3(32, 125), 256, 0, stream>>>((const ushort_t*)a2, (const ushort_t*)b2,
                                                 b_bias, KP, N_TYPE, N_TYPE, out);
}

// Round 8
// 306.715 us; speedup vs baseline: 1.8764x; 1.8764x over previous
//
#include <hip/hip_runtime.h>
#include <hip/hip_bf16.h>
#include <math.h>

#define N_ENT   50000
#define N_REL   237
#define N_TYPE  4000
#define DE      100
#define NOUT    128
#define DT      200
#define N_EDGE  800000
#define B_SZ    4096
#define ALPHA   0.2f
#define EPS     1e-5f
#define NUM_FILT 32
#define CONV_W_OUT 60
#define POOL_W  30
#define FC_LEN  960
#define KP      224

typedef unsigned short ushort_t;
typedef __attribute__((ext_vector_type(8))) short bf16x8;
typedef __attribute__((ext_vector_type(4))) float f32x4;

// ---------------- zero fill ----------------
__global__ void k_fill0(float4* p, int n) {
    int i = blockIdx.x * blockDim.x + threadIdx.x;
    if (i < n) p[i] = make_float4(0.f, 0.f, 0.f, 0.f);
}

// ---------------- diagnostic fill (f32) ----------------
__global__ void k_fillconst(float* p, long n, float val) {
    long i = (long)blockIdx.x * blockDim.x + threadIdx.x;
    long stride = (long)gridDim.x * blockDim.x;
    for (; i < n; i += stride) p[i] = val;
}

// ---------------- batch membership flags ----------------
__global__ void k_flags(const int* xb, int* flags) {
    int i = blockIdx.x * blockDim.x + threadIdx.x;
    if (i < B_SZ) flags[xb[i]] = 1;
}

// ---------------- compact slot ids + slot->entity map ----------------
__global__ void k_slots(int* flags, int* counter, int* slotent) {
    int i = blockIdx.x * blockDim.x + threadIdx.x;
    if (i >= N_ENT) return;
    if (flags[i]) {
        int s = atomicAdd(counter, 1);
        flags[i] = 1 + s;
        slotent[s] = i;
    }
}

// ---------------- wa1/wa2/rw precompute ----------------
__global__ void k_prep(const float* Wf, const float* a_vec, const float* Rw,
                       float* wa1, float* wa2, float* rw) {
    __shared__ float sa[2 * NOUT];
    __shared__ float swa2[DE];
    int t = threadIdx.x;
    sa[t] = a_vec[t];
    __syncthreads();
    if (t < DE) {
        float s1 = 0.f, s2 = 0.f;
        for (int j = 0; j < NOUT; j++) {
            float w = Wf[t * NOUT + j];
            s1 += w * sa[j];
            s2 += w * sa[NOUT + j];
        }
        wa1[t] = s1; wa2[t] = s2; swa2[t] = s2;
    }
    __syncthreads();
    if (t < N_REL) {
        float s = 0.f;
        for (int k = 0; k < DE; k++) s += Rw[t * DE + k] * swa2[k];
        rw[t] = s;
    }
}

// ---------------- per-entity dots: ha = E_w.wa1, ew = E_w.wa2 ----------------
__global__ void k_entdots(const float* Ew, const float* wa1, const float* wa2,
                          float* ha, float* ew) {
    int wid = blockIdx.x * 4 + (threadIdx.x >> 6);
    int lane = threadIdx.x & 63;
    if (wid >= N_ENT) return;
    float s1 = 0.f, s2 = 0.f;
    if (lane < DE / 2) {
        const float2* p = (const float2*)(Ew + (size_t)wid * DE);
        float2 v = p[lane];
        s1 = v.x * wa1[2 * lane] + v.y * wa1[2 * lane + 1];
        s2 = v.x * wa2[2 * lane] + v.y * wa2[2 * lane + 1];
    }
    for (int off = 32; off > 0; off >>= 1) {
        s1 += __shfl_down(s1, off);
        s2 += __shfl_down(s2, off);
    }
    if (lane == 0) { ha[wid] = s1; ew[wid] = s2; }
}

// ---------------- edge bucket count ----------------
__global__ void k_count(const int* ei, const int* flags, int* ecount) {
    int e = blockIdx.x * blockDim.x + threadIdx.x;
    if (e >= N_EDGE) return;
    int s = flags[ei[N_EDGE + e]];
    if (s) atomicAdd(&ecount[s - 1], 1);
}

// ---------------- exclusive scan over 4096 counts (1 block, 256 thr) ----------------
__global__ void k_scan(const int* ecount, int* eoff, int* epos) {
    __shared__ int loc[4096];
    __shared__ int tot[256];
    int t = threadIdx.x;
    int base = t * 16;
    int run = 0;
    for (int i = 0; i < 16; i++) { loc[base + i] = run; run += ecount[base + i]; }
    tot[t] = run;
    __syncthreads();
    for (int off = 1; off < 256; off <<= 1) {
        int u = (t >= off) ? tot[t - off] : 0;
        __syncthreads();
        tot[t] += u;
        __syncthreads();
    }
    int ex = tot[t] - run;   // exclusive prefix of this chunk
    for (int i = 0; i < 16; i++) {
        int o = ex + loc[base + i];
        eoff[base + i] = o;
        epos[base + i] = o;
    }
}

// ---------------- scatter active edges into buckets ----------------
__global__ void k_scatter(const int* ei, const int* et, const int* flags,
                          int* epos, int2* ebuck) {
    int e = blockIdx.x * blockDim.x + threadIdx.x;
    if (e >= N_EDGE) return;
    int s = flags[ei[N_EDGE + e]];
    if (!s) return;
    int idx = atomicAdd(&epos[s - 1], 1);
    ebuck[idx] = make_int2(ei[e], et[e]);
}

// ---------------- per-slot aggregation: no atomics ----------------
__global__ void k_agg(const int* counter, const int* ecount, const int* eoff,
                      const int* slotent, const int2* ebuck,
                      const float* Ew, const float* Rw,
                      const float* ha, const float* ew, const float* rw,
                      float* aggc) {
    int slot = blockIdx.x;
    if (slot >= counter[0]) return;
    int t = threadIdx.x;
    int n = ecount[slot], o = eoff[slot];
    float hae = ha[slotent[slot]];
    float acc = 0.f, den = 0.f;
    for (int j = 0; j < n; j++) {
        int2 p = ebuck[o + j];
        float sc = hae + ew[p.x] - rw[p.y];
        sc = sc >= 0.f ? sc : ALPHA * sc;
        float ex = expf(sc);
        den += ex;
        if (t < DE) acc += ex * (Ew[(size_t)p.x * DE + t] - Rw[(size_t)p.y * DE + t]);
    }
    if (t < DE) aggc[(size_t)slot * DE + t] = acc / (den + 1e-16f);
}

// -------- gather + project + elu + conv-u partial stats (no atomics) --------
// u = conv(raw x). bn1+bn3 fold into affine A_c*u+B_c (conv bias & bn1 shift cancel).
__global__ void k_gatherconv(const int* xb, const int* flags, const float* aggc,
                             const float* Wf, const float* convw,
                             float* ebuf, float* gps, float* gpq, float* cpart) {
    __shared__ float row[DE];
    __shared__ float xs[NOUT];
    __shared__ float cw[NUM_FILT * 9];
    __shared__ float red[NOUT], red2[NOUT];
    int b = blockIdx.x, t = threadIdx.x;
    int slot = flags[xb[b]] - 1;
    if (t < DE) row[t] = aggc[(size_t)slot * DE + t];
    for (int i = t; i < NUM_FILT * 9; i += 128) cw[i] = convw[i];
    __syncthreads();
    float acc = 0.f;
    for (int k = 0; k < DE; k++) acc += row[k] * Wf[k * NOUT + t];
    float x = acc > 0.f ? acc : expm1f(acc);
    xs[t] = x;
    ebuf[(size_t)b * NOUT + t] = x;
    red[t] = x; red2[t] = x * x;
    __syncthreads();
    for (int s = 64; s > 0; s >>= 1) {
        if (t < s) { red[t] += red[t + s]; red2[t] += red2[t + s]; }
        __syncthreads();
    }
    if (t == 0) { gps[b] = red[0]; gpq[b] = red2[0]; }
    // conv-u partials: t -> (c = t>>2, wg = t&3), w = wg+4i, i<15
    int c = t >> 2, wg = t & 3;
    float ls = 0.f, lq = 0.f;
    for (int i = 0; i < 15; i++) {
        int w = wg + 4 * i;
        float u = 0.f;
        #pragma unroll
        for (int j = 0; j < 9; j++) u += cw[c * 9 + j] * xs[2 * w + j];
        ls += u; lq += u * u;
    }
    __syncthreads();
    red[t] = ls; red2[t] = lq;
    __syncthreads();
    if (wg == 0) {
        float s = red[t] + red[t + 1] + red[t + 2] + red[t + 3];
        float q = red2[t] + red2[t + 1] + red2[t + 2] + red2[t + 3];
        cpart[b * 64 + c] = s;
        cpart[b * 64 + 32 + c] = q;
    }
}

// ---------------- reduce bn1 stats -> s1 ----------------
__global__ void k_red1(const float* gps, const float* gpq, const float* g1, float* bn1stat) {
    __shared__ float r1[256], r2[256];
    int t = threadIdx.x;
    float s = 0.f, q = 0.f;
    for (int b = t; b < B_SZ; b += 256) { s += gps[b]; q += gpq[b]; }
    r1[t] = s; r2[t] = q;
    __syncthreads();
    for (int k = 128; k > 0; k >>= 1) {
        if (t < k) { r1[t] += r1[t + k]; r2[t] += r2[t + k]; }
        __syncthreads();
    }
    if (t == 0) {
        float N = (float)(B_SZ * NOUT);
        float mean = r1[0] / N;
        float var = r2[0] / N - mean * mean;
        bn1stat[2] = g1[0] * rsqrtf(var + EPS);
    }
}

// ---------------- reduce u stats per filter -> A_c, B_c ----------------
__global__ void k_redAB(const float* cpart, const float* bn1stat,
                        const float* g3, const float* b3, float* AB) {
    __shared__ float r1[256], r2[256];
    int c = blockIdx.x, t = threadIdx.x;
    float s = 0.f, q = 0.f;
    for (int b = t; b < B_SZ; b += 256) { s += cpart[b * 64 + c]; q += cpart[b * 64 + 32 + c]; }
    r1[t] = s; r2[t] = q;
    __syncthreads();
    for (int k = 128; k > 0; k >>= 1) {
        if (t < k) { r1[t] += r1[t + k]; r2[t] += r2[t + k]; }
        __syncthreads();
    }
    if (t == 0) {
        float N = (float)(B_SZ * CONV_W_OUT);
        float mu = r1[0] / N;
        float vu = r2[0] / N - mu * mu;
        float s1 = bn1stat[2];
        float A = g3[c] * s1 * rsqrtf(s1 * s1 * vu + EPS);
        AB[c] = A;
        AB[32 + c] = b3[c] - A * mu;
    }
}

// ---------------- recompute conv + affine(bn1+bn3) + relu + pool ----------------
__global__ void k_pool(const float* ebuf, const float* convw, const float* AB,
                       __hip_bfloat16* pooled) {
    __shared__ float xs[NOUT];
    __shared__ float cw[NUM_FILT * 9];
    __shared__ float sA[32], sB[32];
    int b = blockIdx.x, t = threadIdx.x;
    xs[t] = ebuf[(size_t)b * NOUT + t];
    for (int i = t; i < NUM_FILT * 9; i += 128) cw[i] = convw[i];
    if (t < 32) { sA[t] = AB[t]; sB[t] = AB[32 + t]; }
    __syncthreads();
    int c = t >> 2, wg = t & 3;
    float A = sA[c], Bv = sB[c];
    for (int i = 0; i < 8; i++) {
        int w2 = wg + 4 * i;
        if (w2 < POOL_W) {
            int w = 2 * w2;
            float u0 = 0.f, u1 = 0.f;
            #pragma unroll
            for (int j = 0; j < 9; j++) {
                float cv = cw[c * 9 + j];
                u0 += cv * xs[2 * w + j];
                u1 += cv * xs[2 * w + 2 + j];
            }
            float z0 = fmaxf(A * u0 + Bv, 0.f);
            float z1 = fmaxf(A * u1 + Bv, 0.f);
            pooled[((size_t)b * NUM_FILT + c) * POOL_W + w2] = __float2bfloat16(fmaxf(z0, z1));
        }
    }
}

// ---------------- repack fc_w f32 [200,960] -> bf16 [224,960] ----------------
__global__ void k_pad_fcw(const float* fcw, __hip_bfloat16* bfc) {
    int i = blockIdx.x * blockDim.x + threadIdx.x;
    if (i >= KP * FC_LEN) return;
    bfc[i] = __float2bfloat16((i < DT * FC_LEN) ? fcw[i] : 0.f);
}

// ---------------- repack T_w f32 [4000,200] -> bf16 [4000,224] ----------------
__global__ void k_pad_tw(const float* tw, __hip_bfloat16* b2) {
    int i = blockIdx.x * blockDim.x + threadIdx.x;
    if (i >= N_TYPE * KP) return;
    int n = i / KP, k = i - n * KP;
    b2[i] = __float2bfloat16((k < DT) ? tw[n * DT + k] : 0.f);
}

// ---------------- MFMA GEMM (f32 out). MODE1 fuses bias+sigmoid ----------------
template<int MODE>
__launch_bounds__(256)
__global__ void k_gemm(const ushort_t* A, const ushort_t* Bm, const float* bias,
                       int K, int ldc, int nbias, float* Cf) {
    int wave = threadIdx.x >> 6, lane = threadIdx.x & 63;
    int m0 = blockIdx.x * 128 + wave * 32;
    int n0 = blockIdx.y * 32;
    int rsel = lane & 15, ksel = (lane >> 4) * 8;
    const ushort_t* pa0 = A + (size_t)(m0 + rsel) * K + ksel;
    const ushort_t* pa1 = pa0 + (size_t)16 * K;
    const ushort_t* pb0 = Bm + (size_t)(n0 + rsel) * K + ksel;
    const ushort_t* pb1 = pb0 + (size_t)16 * K;
    f32x4 acc00 = {0.f, 0.f, 0.f, 0.f};
    f32x4 acc01 = acc00, acc10 = acc00, acc11 = acc00;
    for (int k = 0; k < K; k += 32) {
        bf16x8 a0 = *(const bf16x8*)(pa0 + k);
        bf16x8 a1 = *(const bf16x8*)(pa1 + k);
        bf16x8 b0 = *(const bf16x8*)(pb0 + k);
        bf16x8 b1 = *(const bf16x8*)(pb1 + k);
        acc00 = __builtin_amdgcn_mfma_f32_16x16x32_bf16(a0, b0, acc00, 0, 0, 0);
        acc01 = __builtin_amdgcn_mfma_f32_16x16x32_bf16(a0, b1, acc01, 0, 0, 0);
        acc10 = __builtin_amdgcn_mfma_f32_16x16x32_bf16(a1, b0, acc10, 0, 0, 0);
        acc11 = __builtin_amdgcn_mfma_f32_16x16x32_bf16(a1, b1, acc11, 0, 0, 0);
    }
    int rbase = (lane >> 4) * 4, col = lane & 15;
    auto store_tile = [&](f32x4 acc, int mi, int nj) {
        #pragma unroll
        for (int r2 = 0; r2 < 4; r2++) {
            int row = m0 + mi * 16 + rbase + r2;
            int cc = n0 + nj * 16 + col;
            float v = acc[r2];
            if (MODE == 0) {
                float bb = (cc < nbias) ? bias[cc] : 0.f;
                Cf[(size_t)row * ldc + cc] = v + bb;
            } else {
                Cf[(size_t)row * ldc + cc] = 1.f / (1.f + expf(-(v + bias[cc])));
            }
        }
    };
    store_tile(acc00, 0, 0); store_tile(acc01, 0, 1);
    store_tile(acc10, 1, 0); store_tile(acc11, 1, 1);
}

// ---------------- bn2 stats ----------------
__global__ void k_bn2stats(const float* fcout, const float* g, const float* bb,
                           float* scale, float* shift) {
    __shared__ float rs[256], rq[256];
    int t = blockIdx.x;
    int tid = threadIdx.x;
    float s = 0.f, q = 0.f;
    for (int b = tid; b < B_SZ; b += 256) {
        float v = fcout[(size_t)b * KP + t];
        s += v; q += v * v;
    }
    rs[tid] = s; rq[tid] = q;
    __syncthreads();
    for (int k = 128; k > 0; k >>= 1) {
        if (tid < k) { rs[tid] += rs[tid + k]; rq[tid] += rq[tid + k]; }
        __syncthreads();
    }
    if (tid == 0) {
        float mean = rs[0] / (float)B_SZ;
        float var = rq[0] / (float)B_SZ - mean * mean;
        float sc = g[t] * rsqrtf(var + EPS);
        scale[t] = sc;
        shift[t] = bb[t] - mean * sc;
    }
}

// ---------------- bn2 apply + relu -> bf16 A2 [B,224] ----------------
__global__ void k_bn2apply(const float* fcout, const float* scale, const float* shift,
                           __hip_bfloat16* a2) {
    int i = blockIdx.x * blockDim.x + threadIdx.x;
    if (i >= B_SZ * KP) return;
    int t = i % KP;
    float v = 0.f;
    if (t < DT) {
        v = fcout[i] * scale[t] + shift[t];
        v = fmaxf(v, 0.f);
    }
    a2[i] = __float2bfloat16(v);
}

extern "C" void kernel_launch(void* const* d_in, const int* in_sizes, int n_in,
                              void* d_out, int out_size, void* d_ws, size_t ws_size,
                              hipStream_t stream) {
    (void)in_sizes; (void)n_in;
    const int*   x_batch = (const int*)d_in[0];
    const int*   ei      = (const int*)d_in[1];
    const int*   etype   = (const int*)d_in[2];
    const float* E_w     = (const float*)d_in[3];
    const float* R_w     = (const float*)d_in[4];
    const float* T_w     = (const float*)d_in[5];
    const float* W_f     = (const float*)d_in[6];
    const float* a_vec   = (const float*)d_in[7];
    const float* conv_w  = (const float*)d_in[8];
    const float* bn1_g   = (const float*)d_in[10];
    const float* bn3_g   = (const float*)d_in[12];
    const float* bn3_b   = (const float*)d_in[13];
    const float* bn2_g   = (const float*)d_in[14];
    const float* bn2_b   = (const float*)d_in[15];
    const float* fc_w    = (const float*)d_in[16];
    const float* fc_b    = (const float*)d_in[17];
    const float* b_bias  = (const float*)d_in[18];
    float* out           = (float*)d_out;
    long outn = (long)out_size;

    // ---- ws layout (max 4,279,552 B) ----
    const size_t WS_NEEDED = 4279552;
    if (ws_size < WS_NEEDED) {
        k_fillconst<<<2048, 256, 0, stream>>>(out, outn, 50.f);
        return;
    }
    char* ws = (char*)d_ws;
    float* wa1      = (float*)(ws + 0);
    float* wa2      = (float*)(ws + 512);
    float* rw       = (float*)(ws + 1024);
    float* bn1stat  = (float*)(ws + 2048);       // [2] = s1
    float* AB       = (float*)(ws + 2304);       // A[0..31], B[32..63]
    int*   counter  = (int*)  (ws + 2560);
    float* bn2scale = (float*)(ws + 2816);
    float* bn2shift = (float*)(ws + 3840);
    float* gps      = (float*)(ws + 4864);       // [4096] bn1 partial sums
    float* gpq      = (float*)(ws + 21248);      // [4096] bn1 partial sumsq
    float* cpart    = (float*)(ws + 37632);      // [4096][64] conv-u partials
    int*   flags    = (int*)  (ws + 1086208);    // [50000]
    int*   slotent  = (int*)  (ws + 1286400);    // [4096]
    int*   ecount   = (int*)  (ws + 1302784);    // [4096]
    int*   eoff     = (int*)  (ws + 1319168);    // [4096]
    int*   epos     = (int*)  (ws + 1335552);    // [4096]
    float* ha       = (float*)(ws + 1351936);    // [50000]
    float* ew       = (float*)(ws + 1552128);    // [50000]
    float* ebuf     = (float*)(ws + 1752320);    // [4096,128] f32 -> ends 3,849,472
    __hip_bfloat16* bfc = (__hip_bfloat16*)(ws + 3849472);  // [224,960] -> ends 4,279,552
    // late-phase overlays (all prior occupants dead):
    __hip_bfloat16* a2 = (__hip_bfloat16*)(ws + 4864);      // [4096,224] -> ends 1,839,872
    __hip_bfloat16* b2 = (__hip_bfloat16*)(ws + 1840128);   // [4000,224] -> ends 3,632,128
    // d_out scratch (65.5 MB; final GEMM reads only ws, rewrites all of d_out)
    __hip_bfloat16* pooled = (__hip_bfloat16*)((char*)d_out + 0);        // 7.86 MB
    float* fcout    = (float*)((char*)d_out + 8388608);                  // 3.67 MB
    int2*  ebuck    = (int2*) ((char*)d_out + 16777216);                 // 6.4 MB worst case
    float* aggc     = (float*)((char*)d_out + 25165824);                 // 1.6 MB

    // 1. zero: counter (256B), flags+slotent+ecount (232,960 B contiguous)
    k_fill0<<<1, 32, 0, stream>>>((float4*)counter, 16);
    k_fill0<<<57, 256, 0, stream>>>((float4*)flags, 232960 / 16);
    // 2. flags -> compact slots
    k_flags<<<16, 256, 0, stream>>>(x_batch, flags);
    k_slots<<<196, 256, 0, stream>>>(flags, counter, slotent);
    // 3. rank-1 precompute
    k_prep<<<1, 256, 0, stream>>>(W_f, a_vec, R_w, wa1, wa2, rw);
    // 4. per-entity dots
    k_entdots<<<12500, 256, 0, stream>>>(E_w, wa1, wa2, ha, ew);
    // 5. group edges by destination slot
    k_count<<<3125, 256, 0, stream>>>(ei, flags, ecount);
    k_scan<<<1, 256, 0, stream>>>(ecount, eoff, epos);
    k_scatter<<<3125, 256, 0, stream>>>(ei, etype, flags, epos, ebuck);
    // 6. per-slot softmax-weighted aggregation (atomic-free)
    k_agg<<<4096, 128, 0, stream>>>(counter, ecount, eoff, slotent, ebuck,
                                    E_w, R_w, ha, ew, rw, aggc);
    // 7. gather + project + elu + conv-u partial stats
    k_gatherconv<<<4096, 128, 0, stream>>>(x_batch, flags, aggc, W_f, conv_w,
                                           ebuf, gps, gpq, cpart);
    // 8. stat reductions -> s1, A_c, B_c
    k_red1<<<1, 256, 0, stream>>>(gps, gpq, bn1_g, bn1stat);
    k_redAB<<<32, 256, 0, stream>>>(cpart, bn1stat, bn3_g, bn3_b, AB);
    // 9. conv recompute + fused bn1/bn3 affine + relu + pool
    k_pool<<<4096, 128, 0, stream>>>(ebuf, conv_w, AB, pooled);
    // 10. FC GEMM
    k_pad_fcw<<<840, 256, 0, stream>>>(fc_w, bfc);
    k_gemm<0><<<dim3(32, 7), 256, 0, stream>>>((const ushort_t*)pooled, (const ushort_t*)bfc,
                                               fc_b, FC_LEN, KP, DT, fcout);
    // 11. bn2
    k_bn2stats<<<200, 256, 0, stream>>>(fcout, bn2_g, bn2_b, bn2scale, bn2shift);
    k_bn2apply<<<3584, 256, 0, stream>>>(fcout, bn2scale, bn2shift, a2);
    // 12. logits GEMM + bias + sigmoid -> f32 out
    k_pad_tw<<<3500, 256, 0, stream>>>(T_w, b2);
    k_gemm<1><<<dim3(32, 125), 256, 0, stream>>>((const ushort_t*)a2, (const ushort_t*)b2,
                                                 b_bias, KP, N_TYPE, N_TYPE, out);
}

// Round 9
// 297.348 us; speedup vs baseline: 1.9355x; 1.0315x over previous
//
#include <hip/hip_runtime.h>
#include <hip/hip_bf16.h>
#include <math.h>

#define N_ENT   50000
#define N_REL   237
#define N_TYPE  4000
#define DE      100
#define NOUT    128
#define DT      200
#define N_EDGE  800000
#define B_SZ    4096
#define ALPHA   0.2f
#define EPS     1e-5f
#define NUM_FILT 32
#define CONV_W_OUT 60
#define POOL_W  30
#define FC_LEN  960
#define KP      224
#define NTP     4032   // logits N padded to 63*64

typedef unsigned short ushort_t;
typedef __attribute__((ext_vector_type(8))) short bf16x8;
typedef __attribute__((ext_vector_type(4))) float f32x4;

// ---------------- zero fill ----------------
__global__ void k_fill0(float4* p, int n) {
    int i = blockIdx.x * blockDim.x + threadIdx.x;
    if (i < n) p[i] = make_float4(0.f, 0.f, 0.f, 0.f);
}

// ---------------- diagnostic fill (f32) ----------------
__global__ void k_fillconst(float* p, long n, float val) {
    long i = (long)blockIdx.x * blockDim.x + threadIdx.x;
    long stride = (long)gridDim.x * blockDim.x;
    for (; i < n; i += stride) p[i] = val;
}

// ---------------- batch membership flags ----------------
__global__ void k_flags(const int* xb, int* flags) {
    int i = blockIdx.x * blockDim.x + threadIdx.x;
    if (i < B_SZ) flags[xb[i]] = 1;
}

// ---------------- compact slot ids + slot->entity map ----------------
__global__ void k_slots(int* flags, int* counter, int* slotent) {
    int i = blockIdx.x * blockDim.x + threadIdx.x;
    if (i >= N_ENT) return;
    if (flags[i]) {
        int s = atomicAdd(counter, 1);
        flags[i] = 1 + s;
        slotent[s] = i;
    }
}

// ---------------- wa1/wa2/rw precompute ----------------
__global__ void k_prep(const float* Wf, const float* a_vec, const float* Rw,
                       float* wa1, float* wa2, float* rw) {
    __shared__ float sa[2 * NOUT];
    __shared__ float swa2[DE];
    int t = threadIdx.x;
    sa[t] = a_vec[t];
    __syncthreads();
    if (t < DE) {
        float s1 = 0.f, s2 = 0.f;
        for (int j = 0; j < NOUT; j++) {
            float w = Wf[t * NOUT + j];
            s1 += w * sa[j];
            s2 += w * sa[NOUT + j];
        }
        wa1[t] = s1; wa2[t] = s2; swa2[t] = s2;
    }
    __syncthreads();
    if (t < N_REL) {
        float s = 0.f;
        for (int k = 0; k < DE; k++) s += Rw[t * DE + k] * swa2[k];
        rw[t] = s;
    }
}

// ---------------- per-entity dots: ha = E_w.wa1, ew = E_w.wa2 ----------------
__global__ void k_entdots(const float* Ew, const float* wa1, const float* wa2,
                          float* ha, float* ew) {
    int wid = blockIdx.x * 4 + (threadIdx.x >> 6);
    int lane = threadIdx.x & 63;
    if (wid >= N_ENT) return;
    float s1 = 0.f, s2 = 0.f;
    if (lane < DE / 2) {
        const float2* p = (const float2*)(Ew + (size_t)wid * DE);
        float2 v = p[lane];
        s1 = v.x * wa1[2 * lane] + v.y * wa1[2 * lane + 1];
        s2 = v.x * wa2[2 * lane] + v.y * wa2[2 * lane + 1];
    }
    for (int off = 32; off > 0; off >>= 1) {
        s1 += __shfl_down(s1, off);
        s2 += __shfl_down(s2, off);
    }
    if (lane == 0) { ha[wid] = s1; ew[wid] = s2; }
}

// ---------------- edge bucket count ----------------
__global__ void k_count(const int* ei, const int* flags, int* ecount) {
    int e = blockIdx.x * blockDim.x + threadIdx.x;
    if (e >= N_EDGE) return;
    int s = flags[ei[N_EDGE + e]];
    if (s) atomicAdd(&ecount[s - 1], 1);
}

// ---------------- exclusive scan over 4096 counts (1 block, 256 thr) ----------------
__global__ void k_scan(const int* ecount, int* eoff, int* epos) {
    __shared__ int loc[4096];
    __shared__ int tot[256];
    int t = threadIdx.x;
    int base = t * 16;
    int run = 0;
    for (int i = 0; i < 16; i++) { loc[base + i] = run; run += ecount[base + i]; }
    tot[t] = run;
    __syncthreads();
    for (int off = 1; off < 256; off <<= 1) {
        int u = (t >= off) ? tot[t - off] : 0;
        __syncthreads();
        tot[t] += u;
        __syncthreads();
    }
    int ex = tot[t] - run;
    for (int i = 0; i < 16; i++) {
        int o = ex + loc[base + i];
        eoff[base + i] = o;
        epos[base + i] = o;
    }
}

// ---------------- scatter active edges into buckets ----------------
__global__ void k_scatter(const int* ei, const int* et, const int* flags,
                          int* epos, int2* ebuck) {
    int e = blockIdx.x * blockDim.x + threadIdx.x;
    if (e >= N_EDGE) return;
    int s = flags[ei[N_EDGE + e]];
    if (!s) return;
    int idx = atomicAdd(&epos[s - 1], 1);
    ebuck[idx] = make_int2(ei[e], et[e]);
}

// ---------------- per-slot aggregation: no atomics ----------------
__global__ void k_agg(const int* counter, const int* ecount, const int* eoff,
                      const int* slotent, const int2* ebuck,
                      const float* Ew, const float* Rw,
                      const float* ha, const float* ew, const float* rw,
                      float* aggc) {
    int slot = blockIdx.x;
    if (slot >= counter[0]) return;
    int t = threadIdx.x;
    int n = ecount[slot], o = eoff[slot];
    float hae = ha[slotent[slot]];
    float acc = 0.f, den = 0.f;
    for (int j = 0; j < n; j++) {
        int2 p = ebuck[o + j];
        float sc = hae + ew[p.x] - rw[p.y];
        sc = sc >= 0.f ? sc : ALPHA * sc;
        float ex = expf(sc);
        den += ex;
        if (t < DE) acc += ex * (Ew[(size_t)p.x * DE + t] - Rw[(size_t)p.y * DE + t]);
    }
    if (t < DE) aggc[(size_t)slot * DE + t] = acc / (den + 1e-16f);
}

// -------- gather + project + elu + conv-u partial stats (no atomics) --------
__global__ void k_gatherconv(const int* xb, const int* flags, const float* aggc,
                             const float* Wf, const float* convw,
                             float* ebuf, float* gps, float* gpq, float* cpart) {
    __shared__ float row[DE];
    __shared__ float xs[NOUT];
    __shared__ float cw[NUM_FILT * 9];
    __shared__ float red[NOUT], red2[NOUT];
    int b = blockIdx.x, t = threadIdx.x;
    int slot = flags[xb[b]] - 1;
    if (t < DE) row[t] = aggc[(size_t)slot * DE + t];
    for (int i = t; i < NUM_FILT * 9; i += 128) cw[i] = convw[i];
    __syncthreads();
    float acc = 0.f;
    for (int k = 0; k < DE; k++) acc += row[k] * Wf[k * NOUT + t];
    float x = acc > 0.f ? acc : expm1f(acc);
    xs[t] = x;
    ebuf[(size_t)b * NOUT + t] = x;
    red[t] = x; red2[t] = x * x;
    __syncthreads();
    for (int s = 64; s > 0; s >>= 1) {
        if (t < s) { red[t] += red[t + s]; red2[t] += red2[t + s]; }
        __syncthreads();
    }
    if (t == 0) { gps[b] = red[0]; gpq[b] = red2[0]; }
    int c = t >> 2, wg = t & 3;
    float ls = 0.f, lq = 0.f;
    for (int i = 0; i < 15; i++) {
        int w = wg + 4 * i;
        float u = 0.f;
        #pragma unroll
        for (int j = 0; j < 9; j++) u += cw[c * 9 + j] * xs[2 * w + j];
        ls += u; lq += u * u;
    }
    __syncthreads();
    red[t] = ls; red2[t] = lq;
    __syncthreads();
    if (wg == 0) {
        float s = red[t] + red[t + 1] + red[t + 2] + red[t + 3];
        float q = red2[t] + red2[t + 1] + red2[t + 2] + red2[t + 3];
        cpart[b * 64 + c] = s;
        cpart[b * 64 + 32 + c] = q;
    }
}

// ------- reduce stats per filter -> A_c, B_c (bn1 var computed redundantly/block) -------
__global__ void k_redAB(const float* gps, const float* gpq, const float* cpart,
                        const float* g1, const float* g3, const float* b3, float* AB) {
    __shared__ float r1[256], r2[256], r3[256], r4[256];
    int c = blockIdx.x, t = threadIdx.x;
    float s = 0.f, q = 0.f, cs = 0.f, cq = 0.f;
    for (int b = t; b < B_SZ; b += 256) {
        s += gps[b]; q += gpq[b];
        cs += cpart[b * 64 + c]; cq += cpart[b * 64 + 32 + c];
    }
    r1[t] = s; r2[t] = q; r3[t] = cs; r4[t] = cq;
    __syncthreads();
    for (int k = 128; k > 0; k >>= 1) {
        if (t < k) { r1[t] += r1[t+k]; r2[t] += r2[t+k]; r3[t] += r3[t+k]; r4[t] += r4[t+k]; }
        __syncthreads();
    }
    if (t == 0) {
        float N1 = (float)(B_SZ * NOUT);
        float m1 = r1[0] / N1;
        float v1 = r2[0] / N1 - m1 * m1;
        float s1 = g1[0] * rsqrtf(v1 + EPS);
        float Nc = (float)(B_SZ * CONV_W_OUT);
        float mu = r3[0] / Nc;
        float vu = r4[0] / Nc - mu * mu;
        float A = g3[c] * s1 * rsqrtf(s1 * s1 * vu + EPS);
        AB[c] = A;
        AB[32 + c] = b3[c] - A * mu;
    }
}

// ---------------- conv recompute + fused affine + relu + pool ----------------
__global__ void k_pool(const float* ebuf, const float* convw, const float* AB,
                       __hip_bfloat16* pooled) {
    __shared__ float xs[NOUT];
    __shared__ float cw[NUM_FILT * 9];
    __shared__ float sA[32], sB[32];
    int b = blockIdx.x, t = threadIdx.x;
    xs[t] = ebuf[(size_t)b * NOUT + t];
    for (int i = t; i < NUM_FILT * 9; i += 128) cw[i] = convw[i];
    if (t < 32) { sA[t] = AB[t]; sB[t] = AB[32 + t]; }
    __syncthreads();
    int c = t >> 2, wg = t & 3;
    float A = sA[c], Bv = sB[c];
    for (int i = 0; i < 8; i++) {
        int w2 = wg + 4 * i;
        if (w2 < POOL_W) {
            int w = 2 * w2;
            float u0 = 0.f, u1 = 0.f;
            #pragma unroll
            for (int j = 0; j < 9; j++) {
                float cv = cw[c * 9 + j];
                u0 += cv * xs[2 * w + j];
                u1 += cv * xs[2 * w + 2 + j];
            }
            float z0 = fmaxf(A * u0 + Bv, 0.f);
            float z1 = fmaxf(A * u1 + Bv, 0.f);
            pooled[((size_t)b * NUM_FILT + c) * POOL_W + w2] = __float2bfloat16(fmaxf(z0, z1));
        }
    }
}

// ------- merged repacks: fc_w -> bfc [224,960]; T_w -> b2 [4032,224] (zero pads) -------
__global__ void k_pads(const float* fcw, const float* tw,
                       __hip_bfloat16* bfc, __hip_bfloat16* b2) {
    int i = blockIdx.x * blockDim.x + threadIdx.x;
    if (i < KP * FC_LEN) {
        bfc[i] = __float2bfloat16((i < DT * FC_LEN) ? fcw[i] : 0.f);
    } else {
        int j = i - KP * FC_LEN;
        if (j >= NTP * KP) return;
        int n = j / KP, k = j - n * KP;
        float v = (n < N_TYPE && k < DT) ? tw[n * DT + k] : 0.f;
        b2[j] = __float2bfloat16(v);
    }
}

// ---------------- MFMA GEMM: templated K (pipelining) + NB n-subtiles/wave ----------------
// MODE 0: C = A@B^T + bias (f32).  MODE 1: sigmoid(A@B^T + bias) (f32), store guard cc<N_TYPE
template<int MODE, int K, int NB>
__launch_bounds__(256, 4)
__global__ void k_gemm(const ushort_t* A, const ushort_t* Bm, const float* bias,
                       int ldc, int nbias, float* Cf) {
    int wave = threadIdx.x >> 6, lane = threadIdx.x & 63;
    int m0 = blockIdx.x * 128 + wave * 32;
    int n0 = blockIdx.y * (16 * NB);
    int rsel = lane & 15, ksel = (lane >> 4) * 8;
    const ushort_t* pa0 = A + (size_t)(m0 + rsel) * K + ksel;
    const ushort_t* pa1 = pa0 + (size_t)16 * K;
    const ushort_t* pb[NB];
    #pragma unroll
    for (int j = 0; j < NB; j++) pb[j] = Bm + (size_t)(n0 + j * 16 + rsel) * K + ksel;
    f32x4 acc0[NB], acc1[NB];
    #pragma unroll
    for (int j = 0; j < NB; j++) { acc0[j] = (f32x4){0.f,0.f,0.f,0.f}; acc1[j] = acc0[j]; }
    if constexpr (K <= 256) {
        #pragma unroll
        for (int k = 0; k < K; k += 32) {
            bf16x8 a0 = *(const bf16x8*)(pa0 + k);
            bf16x8 a1 = *(const bf16x8*)(pa1 + k);
            #pragma unroll
            for (int j = 0; j < NB; j++) {
                bf16x8 b = *(const bf16x8*)(pb[j] + k);
                acc0[j] = __builtin_amdgcn_mfma_f32_16x16x32_bf16(a0, b, acc0[j], 0, 0, 0);
                acc1[j] = __builtin_amdgcn_mfma_f32_16x16x32_bf16(a1, b, acc1[j], 0, 0, 0);
            }
        }
    } else {
        #pragma unroll 4
        for (int k = 0; k < K; k += 32) {
            bf16x8 a0 = *(const bf16x8*)(pa0 + k);
            bf16x8 a1 = *(const bf16x8*)(pa1 + k);
            #pragma unroll
            for (int j = 0; j < NB; j++) {
                bf16x8 b = *(const bf16x8*)(pb[j] + k);
                acc0[j] = __builtin_amdgcn_mfma_f32_16x16x32_bf16(a0, b, acc0[j], 0, 0, 0);
                acc1[j] = __builtin_amdgcn_mfma_f32_16x16x32_bf16(a1, b, acc1[j], 0, 0, 0);
            }
        }
    }
    int rbase = (lane >> 4) * 4, col = lane & 15;
    auto store_tile = [&](f32x4 acc, int mrow, int nj) {
        #pragma unroll
        for (int r2 = 0; r2 < 4; r2++) {
            int row = mrow + rbase + r2;
            int cc = n0 + nj * 16 + col;
            float v = acc[r2];
            if (MODE == 0) {
                float bb = (cc < nbias) ? bias[cc] : 0.f;
                Cf[(size_t)row * ldc + cc] = v + bb;
            } else {
                if (cc < nbias)
                    Cf[(size_t)row * ldc + cc] = 1.f / (1.f + expf(-(v + bias[cc])));
            }
        }
    };
    #pragma unroll
    for (int j = 0; j < NB; j++) {
        store_tile(acc0[j], m0, j);
        store_tile(acc1[j], m0 + 16, j);
    }
}

// ---------------- bn2 stats ----------------
__global__ void k_bn2stats(const float* fcout, const float* g, const float* bb,
                           float* scale, float* shift) {
    __shared__ float rs[256], rq[256];
    int t = blockIdx.x;
    int tid = threadIdx.x;
    float s = 0.f, q = 0.f;
    for (int b = tid; b < B_SZ; b += 256) {
        float v = fcout[(size_t)b * KP + t];
        s += v; q += v * v;
    }
    rs[tid] = s; rq[tid] = q;
    __syncthreads();
    for (int k = 128; k > 0; k >>= 1) {
        if (tid < k) { rs[tid] += rs[tid + k]; rq[tid] += rq[tid + k]; }
        __syncthreads();
    }
    if (tid == 0) {
        float mean = rs[0] / (float)B_SZ;
        float var = rq[0] / (float)B_SZ - mean * mean;
        float sc = g[t] * rsqrtf(var + EPS);
        scale[t] = sc;
        shift[t] = bb[t] - mean * sc;
    }
}

// ---------------- bn2 apply + relu -> bf16 A2 [B,224] ----------------
__global__ void k_bn2apply(const float* fcout, const float* scale, const float* shift,
                           __hip_bfloat16* a2) {
    int i = blockIdx.x * blockDim.x + threadIdx.x;
    if (i >= B_SZ * KP) return;
    int t = i % KP;
    float v = 0.f;
    if (t < DT) {
        v = fcout[i] * scale[t] + shift[t];
        v = fmaxf(v, 0.f);
    }
    a2[i] = __float2bfloat16(v);
}

extern "C" void kernel_launch(void* const* d_in, const int* in_sizes, int n_in,
                              void* d_out, int out_size, void* d_ws, size_t ws_size,
                              hipStream_t stream) {
    (void)in_sizes; (void)n_in;
    const int*   x_batch = (const int*)d_in[0];
    const int*   ei      = (const int*)d_in[1];
    const int*   etype   = (const int*)d_in[2];
    const float* E_w     = (const float*)d_in[3];
    const float* R_w     = (const float*)d_in[4];
    const float* T_w     = (const float*)d_in[5];
    const float* W_f     = (const float*)d_in[6];
    const float* a_vec   = (const float*)d_in[7];
    const float* conv_w  = (const float*)d_in[8];
    const float* bn1_g   = (const float*)d_in[10];
    const float* bn3_g   = (const float*)d_in[12];
    const float* bn3_b   = (const float*)d_in[13];
    const float* bn2_g   = (const float*)d_in[14];
    const float* bn2_b   = (const float*)d_in[15];
    const float* fc_w    = (const float*)d_in[16];
    const float* fc_b    = (const float*)d_in[17];
    const float* b_bias  = (const float*)d_in[18];
    float* out           = (float*)d_out;
    long outn = (long)out_size;

    const size_t WS_NEEDED = 4279296;
    if (ws_size < WS_NEEDED) {
        k_fillconst<<<2048, 256, 0, stream>>>(out, outn, 50.f);
        return;
    }
    char* ws = (char*)d_ws;
    float* wa1      = (float*)(ws + 0);
    float* wa2      = (float*)(ws + 512);
    float* rw       = (float*)(ws + 1024);
    float* AB       = (float*)(ws + 2048);       // A[0..31], B[32..63]
    float* bn2scale = (float*)(ws + 2816);
    float* bn2shift = (float*)(ws + 3840);
    float* gps      = (float*)(ws + 4864);       // [4096]
    float* gpq      = (float*)(ws + 21248);      // [4096]
    float* cpart    = (float*)(ws + 37632);      // [4096][64] -> ends 1,086,208
    int*   counter  = (int*)  (ws + 1086208);    // zero-region start
    int*   flags    = (int*)  (ws + 1086464);    // [50000]
    int*   slotent  = (int*)  (ws + 1286464);    // [4096]
    int*   ecount   = (int*)  (ws + 1302848);    // [4096] -> zero-region ends 1,319,232
    int*   eoff     = (int*)  (ws + 1319232);    // [4096]
    int*   epos     = (int*)  (ws + 1335616);    // [4096]
    float* ha       = (float*)(ws + 1352064);    // [50000]
    float* ew       = (float*)(ws + 1552064);    // [50000]
    float* ebuf     = (float*)(ws + 1752064);    // [4096,128] f32 -> ends 3,849,216
    __hip_bfloat16* bfc = (__hip_bfloat16*)(ws + 3849216);   // [224,960] -> ends 4,279,296
    // late-phase overlays (prior occupants dead):
    __hip_bfloat16* a2 = (__hip_bfloat16*)(ws + 4864);       // [4096,224] -> ends 1,839,872
    __hip_bfloat16* b2 = (__hip_bfloat16*)(ws + 1840128);    // [4032,224] -> ends 3,646,464
    // d_out scratch (65.5 MB; final GEMM reads only ws, rewrites all of d_out)
    __hip_bfloat16* pooled = (__hip_bfloat16*)((char*)d_out + 0);        // 7.86 MB
    float* fcout    = (float*)((char*)d_out + 8388608);                  // 3.67 MB
    int2*  ebuck    = (int2*) ((char*)d_out + 16777216);                 // up to 6.4 MB
    float* aggc     = (float*)((char*)d_out + 25165824);                 // 1.6 MB

    // 1. zero counter+flags+slotent+ecount in one contiguous fill (233,024 B)
    k_fill0<<<57, 256, 0, stream>>>((float4*)counter, 233024 / 16);
    // 2. flags -> compact slots
    k_flags<<<16, 256, 0, stream>>>(x_batch, flags);
    k_slots<<<196, 256, 0, stream>>>(flags, counter, slotent);
    // 3. rank-1 precompute
    k_prep<<<1, 256, 0, stream>>>(W_f, a_vec, R_w, wa1, wa2, rw);
    // 4. per-entity dots
    k_entdots<<<12500, 256, 0, stream>>>(E_w, wa1, wa2, ha, ew);
    // 5. group edges by destination slot
    k_count<<<3125, 256, 0, stream>>>(ei, flags, ecount);
    k_scan<<<1, 256, 0, stream>>>(ecount, eoff, epos);
    k_scatter<<<3125, 256, 0, stream>>>(ei, etype, flags, epos, ebuck);
    // 6. per-slot softmax-weighted aggregation
    k_agg<<<4096, 128, 0, stream>>>(counter, ecount, eoff, slotent, ebuck,
                                    E_w, R_w, ha, ew, rw, aggc);
    // 7. gather + project + elu + conv-u partial stats
    k_gatherconv<<<4096, 128, 0, stream>>>(x_batch, flags, aggc, W_f, conv_w,
                                           ebuf, gps, gpq, cpart);
    // 8. stat reductions -> A_c, B_c (bn1 folded in)
    k_redAB<<<32, 256, 0, stream>>>(gps, gpq, cpart, bn1_g, bn3_g, bn3_b, AB);
    // 9. conv recompute + fused affine + relu + pool
    k_pool<<<4096, 128, 0, stream>>>(ebuf, conv_w, AB, pooled);
    // 10. merged repacks (after ebuf death)
    k_pads<<<4368, 256, 0, stream>>>(fc_w, T_w, bfc, b2);
    // 11. FC GEMM: K=960, NB=2 -> fcout f32 [4096,224]
    k_gemm<0, FC_LEN, 2><<<dim3(32, 7), 256, 0, stream>>>(
        (const ushort_t*)pooled, (const ushort_t*)bfc, fc_b, KP, DT, fcout);
    // 12. bn2
    k_bn2stats<<<200, 256, 0, stream>>>(fcout, bn2_g, bn2_b, bn2scale, bn2shift);
    k_bn2apply<<<3584, 256, 0, stream>>>(fcout, bn2scale, bn2shift, a2);
    // 13. logits GEMM: K=224, NB=4 -> sigmoid f32 out [4096,4000]
    k_gemm<1, KP, 4><<<dim3(32, 63), 256, 0, stream>>>(
        (const ushort_t*)a2, (const ushort_t*)b2, b_bias, N_TYPE, N_TYPE, out);
}